// Round 10
// baseline (107.680 us; speedup 1.0000x reference)
//
#include <hip/hip_runtime.h>

typedef __attribute__((ext_vector_type(4))) float f32x4;
typedef __attribute__((ext_vector_type(4))) int   i32x4;
typedef __attribute__((ext_vector_type(8))) int   i32x8;

#define DIM 256
#define D4  64    // float4 per row

// async global->LDS, 16B per lane; LDS dest = wave-uniform base + lane*16.
#define GLD_LDS16(g, l) __builtin_amdgcn_global_load_lds(                      \
    (const __attribute__((address_space(1))) void*)(g),                        \
    (__attribute__((address_space(3))) void*)(l), 16, 0, 0)

// wait for all but the newest N VMEM ops, then barrier (counted prefetch).
#define TILE_WAIT(N) asm volatile("s_waitcnt vmcnt(" #N ")\n\ts_barrier" ::: "memory")

// One wave per row. Rows [0,N): exact fp32 pos_sim -> posPart[row] + normalized
// pk -> fp8 e4m3. Rows [N,N+M): normalized nv -> fp8. Block 0 zeroes `out`
// (replaces the hipMemsetAsync dispatch; stream order -> visible to finalize).
__global__ __launch_bounds__(256) void normalize_kernel(
    const float4* __restrict__ pk, const float4* __restrict__ pv,
    const float4* __restrict__ nv, unsigned int* __restrict__ pkn,
    unsigned int* __restrict__ nvn, float* __restrict__ posPart,
    float* __restrict__ out, int N) {
  if (blockIdx.x == 0 && threadIdx.x == 0) out[0] = 0.f;
  int row  = blockIdx.x * 4 + (threadIdx.x >> 6);
  int lane = threadIdx.x & 63;
  if (row < N) {
    float4 x = pk[row * D4 + lane];
    float4 y = pv[row * D4 + lane];
    float skk = x.x*x.x + x.y*x.y + x.z*x.z + x.w*x.w;
    float svv = y.x*y.x + y.y*y.y + y.z*y.z + y.w*y.w;
    float skv = x.x*y.x + x.y*y.y + x.z*y.z + x.w*y.w;
#pragma unroll
    for (int m = 32; m >= 1; m >>= 1) {
      skk += __shfl_xor(skk, m, 64);
      svv += __shfl_xor(svv, m, 64);
      skv += __shfl_xor(skv, m, 64);
    }
    float nk  = fmaxf(sqrtf(skk), 1e-8f);
    float nvv = fmaxf(sqrtf(svv), 1e-8f);
    if (lane == 0) posPart[row] = skv / (nk * nvv);
    float rk = 1.0f / nk;
    int w = __builtin_amdgcn_cvt_pk_fp8_f32(x.x * rk, x.y * rk, 0, false);
    w = __builtin_amdgcn_cvt_pk_fp8_f32(x.z * rk, x.w * rk, w, true);
    pkn[(size_t)row * 64 + lane] = (unsigned int)w;
  } else {
    int r2 = row - N;
    float4 x = nv[r2 * D4 + lane];
    float s = x.x*x.x + x.y*x.y + x.z*x.z + x.w*x.w;
#pragma unroll
    for (int m = 32; m >= 1; m >>= 1) s += __shfl_xor(s, m, 64);
    float rn = 1.0f / fmaxf(sqrtf(s), 1e-8f);
    int w = __builtin_amdgcn_cvt_pk_fp8_f32(x.x * rn, x.y * rn, 0, false);
    w = __builtin_amdgcn_cvt_pk_fp8_f32(x.z * rn, x.w * rn, w, true);
    nvn[(size_t)r2 * 64 + lane] = (unsigned int)w;
  }
}

// Fused fp8 GEMM (MX 16x16x128, unit scales = exact fp8) + exp(sim/2) + row-sum.
// R16: 4 WAVES/SIMD. Per-SIMD accounting of R9 (~33us gemm): MFMA 17.7k cy +
// LDS ~10k + trans ~4k = 8-10us fully overlapped, rest is latency holes --
// and every variant so far ran only 2 waves/SIMD (256 blocks x 8 waves /
// 1024 SIMDs); R8's barrier-free probe showed the same 72% issue-idle. m69:
// 4 waves/SIMD needs VGPR<=128, blocked until now by af(64)+bf(64) state.
// Block -> 1024 thr = 16 waves (1 block/CU, 4 waves/SIMD); wave row-strip
// 64->32 (mi 2): af[2][2]=32 + bf[4]=32 (kb-outer) + acc[2][4]=32 ~= 112
// VGPR, pinned by __launch_bounds__(1024,4). Macro-structure unchanged
// (persistent 256-row panel, 8 cgs, A-in-regs once, 4-deep LDS B, counted
// vmcnt re-derived for stage=2/store=1 issue order). kb-outer returns (reg
// budget); inter-wave overlap at 4 waves/SIMD replaces R9's intra-wave
// interleave. Per-element accumulation still kb0->kb1; epilogue sum order
// unchanged -> absmax 0.
__global__ __launch_bounds__(1024, 4) void gemm_lse_kernel(
    const unsigned char* __restrict__ gA, const unsigned char* __restrict__ gB,
    float* __restrict__ partial, int N) {
  __shared__ unsigned char Bs[4][32768];  // per buf: [2 kb][128 rows][8 chunks]

  const int tid  = threadIdx.x;           // 0..1023
  const int lane = tid & 63;
  const int wv   = tid >> 6;      // 0..15
  const int wm   = wv >> 1;       // 0..7 : 32-row strip of the 256-row panel
  const int wn   = wv & 1;        // 0..1 : 64-col half of the 128-col tile
  const int l15  = lane & 15, q = lane >> 4;
  const int cg    = blockIdx.x;   // 0..7  : 1024-col group
  const int panel = blockIdx.y;   // 0..31 : 256-row panel
  const int row0  = panel * 256;
  const int colBase = cg * 1024;
  const float kLog2eHalf = 0.72134752044448170f;  // log2(e)/2
  const int kUnitScale = 0x7F7F7F7F;              // e8m0 127 = 2^0 per byte

  auto stageB = [&](int t) {
    const unsigned char* src = gB + (size_t)(colBase + t * 128) * 256;
    unsigned char* dst = &Bs[t & 3][0];
    // 1024 threads, 1024 chunks per kb-half: 2 gld_lds per thread per tile.
#pragma unroll
    for (int kb = 0; kb < 2; kb++) {
      int c  = tid;                      // chunk within this kb-half
      int r  = c >> 3;                   // 0..127
      int sc = ((c & 7) ^ (r & 7)) << 4; // pre-swizzled global source col
      GLD_LDS16(src + (size_t)r * 256 + kb * 128 + sc,
                dst + kb * 16384 + c * 16);
    }
  };

  // A fragments straight to registers, once (4 x i32x8 = 8 dwordx4/thread).
  const unsigned char* aB = gA + (size_t)(row0 + wm * 32 + l15) * 256 + q * 32;
  i32x8 af[2][2];
#pragma unroll
  for (int kb = 0; kb < 2; kb++)
#pragma unroll
    for (int mi = 0; mi < 2; mi++)
      af[kb][mi] = *(const i32x8*)(aB + mi * 16 * 256 + kb * 128);
  __builtin_amdgcn_sched_barrier(0);   // pin: A loads issue before B stages

  stageB(0);
  stageB(1);
  stageB(2);
  __builtin_amdgcn_sched_barrier(0);

#pragma unroll
  for (int t = 0; t < 8; t++) {
    // Counted waits, re-derived for issue order {A:8, stage:2/tile, store:1}:
    // retire B(t)'s 2 loads while keeping later stages/stores in flight.
    if      (t == 0) TILE_WAIT(4);
    else if (t == 1) TILE_WAIT(5);
    else if (t == 2) TILE_WAIT(6);
    else if (t == 3) TILE_WAIT(7);
    else if (t == 4) TILE_WAIT(7);
    else if (t == 5) TILE_WAIT(7);
    else if (t == 6) TILE_WAIT(5);
    else             TILE_WAIT(3);

    if (t < 5) {
      stageB(t + 3);
      __builtin_amdgcn_sched_barrier(0);
    }

    const unsigned char* bufB = &Bs[t & 3][0];
    f32x4 acc[2][4];
#pragma unroll
    for (int mi = 0; mi < 2; mi++)
#pragma unroll
      for (int ni = 0; ni < 4; ni++) acc[mi][ni] = (f32x4){0.f, 0.f, 0.f, 0.f};

#pragma unroll
    for (int kb = 0; kb < 2; kb++) {
      i32x8 bf[4];
#pragma unroll
      for (int ni = 0; ni < 4; ni++) {
        int r  = wn * 64 + ni * 16 + l15;           // 0..127
        int c0 = (q * 2)     ^ (r & 7);
        int c1 = (q * 2 + 1) ^ (r & 7);
        i32x4 lo = *(const i32x4*)(bufB + kb * 16384 + r * 128 + c0 * 16);
        i32x4 hi = *(const i32x4*)(bufB + kb * 16384 + r * 128 + c1 * 16);
        bf[ni] = (i32x8){lo.x, lo.y, lo.z, lo.w, hi.x, hi.y, hi.z, hi.w};
      }
#pragma unroll
      for (int mi = 0; mi < 2; mi++)
#pragma unroll
        for (int ni = 0; ni < 4; ni++)
          acc[mi][ni] = __builtin_amdgcn_mfma_scale_f32_16x16x128_f8f6f4(
              bf[ni], af[kb][mi], acc[mi][ni],      // SWAPPED: D[col][row]
              0, 0, 0, kUnitScale, 0, kUnitScale);
    }

    // epilogue (verified form): lane l15 = pk-row within 16; regs span
    // nv-cols. Row-sum over the wave's 64 cols = in-register + 2 shuffles.
    float s0, s1;
#pragma unroll
    for (int mi = 0; mi < 2; mi++) {
      float v = 0.f;
#pragma unroll
      for (int ni = 0; ni < 4; ni++)
#pragma unroll
        for (int rr = 0; rr < 4; rr++)
          v += __builtin_amdgcn_exp2f(acc[mi][ni][rr] * kLog2eHalf);
      v += __shfl_xor(v, 16, 64);
      v += __shfl_xor(v, 32, 64);
      if (mi == 0) s0 = v; else s1 = v;
    }
    // lanes q<2 store the wave's 32 rows (mi = q): one 128B store per wave.
    float o = (q == 0) ? s0 : s1;
    int slab = cg * 16 + t * 2 + wn;                // 64-col slab, 0..127
    if (q < 2)
      partial[(size_t)slab * N + row0 + wm * 32 + q * 16 + l15] = o;
    __builtin_amdgcn_sched_barrier(0);   // pin: store issues before next stage
  }
}

// out = mean(ln(sum_j partial[j][row])) - 0.5*mean(posPart). UNCHANGED
// (partial is [M/64=128][N]).
__global__ __launch_bounds__(256) void finalize_kernel(
    const float* __restrict__ partial, const float* __restrict__ posPart,
    float* __restrict__ out, int N, int slabsPerGroup, float invN) {
  __shared__ float red[4][64];
  int t  = threadIdx.x;
  int rl = t & 63, g = t >> 6;
  int row = blockIdx.x * 64 + rl;
  const float* p = partial + (size_t)(g * slabsPerGroup) * N + row;
  float s = 0.f;
#pragma unroll 8
  for (int j = 0; j < slabsPerGroup; j++) s += p[(size_t)j * N];
  red[g][rl] = s;
  __syncthreads();
  if (t < 64) {
    float tot = red[0][rl] + red[1][rl] + red[2][rl] + red[3][rl];
    float v = __builtin_amdgcn_logf(tot) * 0.69314718055994531f
              - 0.5f * posPart[row];
#pragma unroll
    for (int m = 32; m >= 1; m >>= 1) v += __shfl_xor(v, m, 64);
    if (rl == 0) atomicAdd(out, v * invN);
  }
}

extern "C" void kernel_launch(void* const* d_in, const int* in_sizes, int n_in,
                              void* d_out, int out_size, void* d_ws, size_t ws_size,
                              hipStream_t stream) {
  const float* pk = (const float*)d_in[0];
  const float* pv = (const float*)d_in[1];
  const float* nv = (const float*)d_in[2];
  int N = in_sizes[0] / DIM;   // 8192
  int M = in_sizes[2] / DIM;   // 8192
  float* out = (float*)d_out;

  unsigned char* pkn = (unsigned char*)d_ws;                   // [N,256] fp8
  unsigned char* nvn = pkn + (size_t)N * DIM;                  // [M,256] fp8
  float* partial = (float*)(nvn + (size_t)M * DIM);            // [M/64][N] fp32
  float* posPart = partial + (size_t)(M / 64) * N;             // [N] fp32

  normalize_kernel<<<(N + M) / 4, 256, 0, stream>>>(
      (const float4*)pk, (const float4*)pv, (const float4*)nv,
      (unsigned int*)pkn, (unsigned int*)nvn, posPart, out, N);

  // grid: x = col-group (8), y = row panel (32); 256 blocks x 16 waves.
  gemm_lse_kernel<<<dim3(M / 1024, N / 256), 1024, 0, stream>>>(
      pkn, nvn, partial, N);

  finalize_kernel<<<N / 64, 256, 0, stream>>>(
      partial, posPart, out, N, (M / 64) / 4, 1.0f / (float)N);
}

// Round 11
// 99.366 us; speedup vs baseline: 1.0837x; 1.0837x over previous
//
#include <hip/hip_runtime.h>

typedef __attribute__((ext_vector_type(4))) float f32x4;
typedef __attribute__((ext_vector_type(4))) int   i32x4;
typedef __attribute__((ext_vector_type(8))) int   i32x8;

#define DIM 256
#define D4  64    // float4 per row

// async global->LDS, 16B per lane; LDS dest = wave-uniform base + lane*16.
#define GLD_LDS16(g, l) __builtin_amdgcn_global_load_lds(                      \
    (const __attribute__((address_space(1))) void*)(g),                        \
    (__attribute__((address_space(3))) void*)(l), 16, 0, 0)

// wait for all but the newest N VMEM ops, then barrier (counted prefetch).
#define TILE_WAIT(N) asm volatile("s_waitcnt vmcnt(" #N ")\n\ts_barrier" ::: "memory")

// One wave per row. Rows [0,N): exact fp32 pos_sim -> posPart[row] + normalized
// pk -> fp8 e4m3. Rows [N,N+M): normalized nv -> fp8. Block 0 zeroes `out`
// (replaces the hipMemsetAsync dispatch; stream order -> visible to finalize).
__global__ __launch_bounds__(256) void normalize_kernel(
    const float4* __restrict__ pk, const float4* __restrict__ pv,
    const float4* __restrict__ nv, unsigned int* __restrict__ pkn,
    unsigned int* __restrict__ nvn, float* __restrict__ posPart,
    float* __restrict__ out, int N) {
  if (blockIdx.x == 0 && threadIdx.x == 0) out[0] = 0.f;
  int row  = blockIdx.x * 4 + (threadIdx.x >> 6);
  int lane = threadIdx.x & 63;
  if (row < N) {
    float4 x = pk[row * D4 + lane];
    float4 y = pv[row * D4 + lane];
    float skk = x.x*x.x + x.y*x.y + x.z*x.z + x.w*x.w;
    float svv = y.x*y.x + y.y*y.y + y.z*y.z + y.w*y.w;
    float skv = x.x*y.x + x.y*y.y + x.z*y.z + x.w*y.w;
#pragma unroll
    for (int m = 32; m >= 1; m >>= 1) {
      skk += __shfl_xor(skk, m, 64);
      svv += __shfl_xor(svv, m, 64);
      skv += __shfl_xor(skv, m, 64);
    }
    float nk  = fmaxf(sqrtf(skk), 1e-8f);
    float nvv = fmaxf(sqrtf(svv), 1e-8f);
    if (lane == 0) posPart[row] = skv / (nk * nvv);
    float rk = 1.0f / nk;
    int w = __builtin_amdgcn_cvt_pk_fp8_f32(x.x * rk, x.y * rk, 0, false);
    w = __builtin_amdgcn_cvt_pk_fp8_f32(x.z * rk, x.w * rk, w, true);
    pkn[(size_t)row * 64 + lane] = (unsigned int)w;
  } else {
    int r2 = row - N;
    float4 x = nv[r2 * D4 + lane];
    float s = x.x*x.x + x.y*x.y + x.z*x.z + x.w*x.w;
#pragma unroll
    for (int m = 32; m >= 1; m >>= 1) s += __shfl_xor(s, m, 64);
    float rn = 1.0f / fmaxf(sqrtf(s), 1e-8f);
    int w = __builtin_amdgcn_cvt_pk_fp8_f32(x.x * rn, x.y * rn, 0, false);
    w = __builtin_amdgcn_cvt_pk_fp8_f32(x.z * rn, x.w * rn, w, true);
    nvn[(size_t)r2 * 64 + lane] = (unsigned int)w;
  }
}

// Fused fp8 GEMM (MX 16x16x128, unit scales = exact fp8) + exp(sim/2) + row-sum.
// R17: 4 waves/SIMD via TWO INDEPENDENT 8-WAVE BLOCKS per CU. R10 coupled
// its 16 waves into ONE barrier domain (one 1024-thr block): every TILE_WAIT
// synced 16 waves, per-wave MFMA between barriers halved -> regression. Here
// the same occupancy arrives as 2 mutually-async blocks (m114: when block A
// stalls in TILE_WAIT, block B's waves keep issuing MFMA). Constraints met:
// LDS 64KB/block (B 2-deep x 32KB; 2 blocks = 128 <= 160), VGPR <= 128
// (panel 128 rows: af[2][2]=32 + bf[4]=32 + acc[2][4]=32, launch_bounds
// (512,4)). Grid (8,64) = 512 blocks = 2/CU; cg = linear%8 -> each XCD reads
// one 256KB B col-group + 2MB A (L2-resident). Pipeline: prologue B0; stage
// B(t+1) at start of t (~600cy L2 latency hides under ~1100cy block MFMA);
// steady vmcnt(1) = retire B(t)'s 4 loads, leave younger store in flight.
// Fragment decode / swapped MFMA / kb0->kb1 accumulation / epilogue order
// unchanged from R9 -> absmax 0.
__global__ __launch_bounds__(512, 4) void gemm_lse_kernel(
    const unsigned char* __restrict__ gA, const unsigned char* __restrict__ gB,
    float* __restrict__ partial, int N) {
  __shared__ unsigned char Bs[2][32768];  // per buf: [2 kb][128 rows][8 chunks]

  const int tid  = threadIdx.x;           // 0..511
  const int lane = tid & 63;
  const int wv   = tid >> 6;      // 0..7
  const int wm   = wv >> 1;       // 0..3 : 32-row strip of the 128-row panel
  const int wn   = wv & 1;        // 0..1 : 64-col half of the 128-col tile
  const int l15  = lane & 15, q = lane >> 4;
  const int cg    = blockIdx.x;   // 0..7  : 1024-col group (== XCD id)
  const int panel = blockIdx.y;   // 0..63 : 128-row panel
  const int row0  = panel * 128;
  const int colBase = cg * 1024;
  const float kLog2eHalf = 0.72134752044448170f;  // log2(e)/2
  const int kUnitScale = 0x7F7F7F7F;              // e8m0 127 = 2^0 per byte

  auto stageB = [&](int t) {
    const unsigned char* src = gB + (size_t)(colBase + t * 128) * 256;
    unsigned char* dst = &Bs[t & 1][0];
#pragma unroll
    for (int kb = 0; kb < 2; kb++)
#pragma unroll
      for (int i = 0; i < 2; i++) {
        int c  = i * 512 + tid;            // chunk within this kb-half
        int r  = c >> 3;                   // 0..127
        int sc = ((c & 7) ^ (r & 7)) << 4; // pre-swizzled global source col
        GLD_LDS16(src + (size_t)r * 256 + kb * 128 + sc,
                  dst + kb * 16384 + c * 16);
      }
  };

  // A fragments straight to registers, once (4 x i32x8 = 8 dwordx4/thread).
  const unsigned char* aB = gA + (size_t)(row0 + wm * 32 + l15) * 256 + q * 32;
  i32x8 af[2][2];
#pragma unroll
  for (int kb = 0; kb < 2; kb++)
#pragma unroll
    for (int mi = 0; mi < 2; mi++)
      af[kb][mi] = *(const i32x8*)(aB + mi * 16 * 256 + kb * 128);
  __builtin_amdgcn_sched_barrier(0);   // pin: A loads issue before B stage

  stageB(0);
  __builtin_amdgcn_sched_barrier(0);

#pragma unroll
  for (int t = 0; t < 8; t++) {
    // t=0: drain A+B0 (nothing else in flight). t>=1: B(t)'s 4 loads are the
    // oldest outstanding; the single store from t-1 is younger -> vmcnt(1).
    if (t == 0) TILE_WAIT(0);
    else        TILE_WAIT(1);

    if (t < 7) {                 // stage B(t+1) into buf[(t+1)&1]: that buf
      stageB(t + 1);             // held B(t-1), consumed before this barrier.
      __builtin_amdgcn_sched_barrier(0);
    }

    const unsigned char* bufB = &Bs[t & 1][0];
    f32x4 acc[2][4];
#pragma unroll
    for (int mi = 0; mi < 2; mi++)
#pragma unroll
      for (int ni = 0; ni < 4; ni++) acc[mi][ni] = (f32x4){0.f, 0.f, 0.f, 0.f};

#pragma unroll
    for (int kb = 0; kb < 2; kb++) {
      i32x8 bf[4];
#pragma unroll
      for (int ni = 0; ni < 4; ni++) {
        int r  = wn * 64 + ni * 16 + l15;           // 0..127
        int c0 = (q * 2)     ^ (r & 7);
        int c1 = (q * 2 + 1) ^ (r & 7);
        i32x4 lo = *(const i32x4*)(bufB + kb * 16384 + r * 128 + c0 * 16);
        i32x4 hi = *(const i32x4*)(bufB + kb * 16384 + r * 128 + c1 * 16);
        bf[ni] = (i32x8){lo.x, lo.y, lo.z, lo.w, hi.x, hi.y, hi.z, hi.w};
      }
#pragma unroll
      for (int mi = 0; mi < 2; mi++)
#pragma unroll
        for (int ni = 0; ni < 4; ni++)
          acc[mi][ni] = __builtin_amdgcn_mfma_scale_f32_16x16x128_f8f6f4(
              bf[ni], af[kb][mi], acc[mi][ni],      // SWAPPED: D[col][row]
              0, 0, 0, kUnitScale, 0, kUnitScale);
    }

    // epilogue (verified form): lane l15 = pk-row within 16; regs span
    // nv-cols. Row-sum over the wave's 64 cols = in-register + 2 shuffles.
    float s0, s1;
#pragma unroll
    for (int mi = 0; mi < 2; mi++) {
      float v = 0.f;
#pragma unroll
      for (int ni = 0; ni < 4; ni++)
#pragma unroll
        for (int rr = 0; rr < 4; rr++)
          v += __builtin_amdgcn_exp2f(acc[mi][ni][rr] * kLog2eHalf);
      v += __shfl_xor(v, 16, 64);
      v += __shfl_xor(v, 32, 64);
      if (mi == 0) s0 = v; else s1 = v;
    }
    // lanes q<2 store the wave's 32 rows (mi = q): one 128B store per wave.
    float o = (q == 0) ? s0 : s1;
    int slab = cg * 16 + t * 2 + wn;                // 64-col slab, 0..127
    if (q < 2)
      partial[(size_t)slab * N + row0 + wm * 32 + q * 16 + l15] = o;
    __builtin_amdgcn_sched_barrier(0);   // pin: store issues before next stage
  }
}

// out = mean(ln(sum_j partial[j][row])) - 0.5*mean(posPart). UNCHANGED
// (partial is [M/64=128][N]).
__global__ __launch_bounds__(256) void finalize_kernel(
    const float* __restrict__ partial, const float* __restrict__ posPart,
    float* __restrict__ out, int N, int slabsPerGroup, float invN) {
  __shared__ float red[4][64];
  int t  = threadIdx.x;
  int rl = t & 63, g = t >> 6;
  int row = blockIdx.x * 64 + rl;
  const float* p = partial + (size_t)(g * slabsPerGroup) * N + row;
  float s = 0.f;
#pragma unroll 8
  for (int j = 0; j < slabsPerGroup; j++) s += p[(size_t)j * N];
  red[g][rl] = s;
  __syncthreads();
  if (t < 64) {
    float tot = red[0][rl] + red[1][rl] + red[2][rl] + red[3][rl];
    float v = __builtin_amdgcn_logf(tot) * 0.69314718055994531f
              - 0.5f * posPart[row];
#pragma unroll
    for (int m = 32; m >= 1; m >>= 1) v += __shfl_xor(v, m, 64);
    if (rl == 0) atomicAdd(out, v * invN);
  }
}

extern "C" void kernel_launch(void* const* d_in, const int* in_sizes, int n_in,
                              void* d_out, int out_size, void* d_ws, size_t ws_size,
                              hipStream_t stream) {
  const float* pk = (const float*)d_in[0];
  const float* pv = (const float*)d_in[1];
  const float* nv = (const float*)d_in[2];
  int N = in_sizes[0] / DIM;   // 8192
  int M = in_sizes[2] / DIM;   // 8192
  float* out = (float*)d_out;

  unsigned char* pkn = (unsigned char*)d_ws;                   // [N,256] fp8
  unsigned char* nvn = pkn + (size_t)N * DIM;                  // [M,256] fp8
  float* partial = (float*)(nvn + (size_t)M * DIM);            // [M/64][N] fp32
  float* posPart = partial + (size_t)(M / 64) * N;             // [N] fp32

  normalize_kernel<<<(N + M) / 4, 256, 0, stream>>>(
      (const float4*)pk, (const float4*)pv, (const float4*)nv,
      (unsigned int*)pkn, (unsigned int*)nvn, posPart, out, N);

  // grid: x = col-group (8), y = 128-row panel (64); 512 blocks = 2/CU.
  gemm_lse_kernel<<<dim3(M / 1024, N / 128), 512, 0, stream>>>(
      pkn, nvn, partial, N);

  finalize_kernel<<<N / 64, 256, 0, stream>>>(
      partial, posPart, out, N, (M / 64) / 4, 1.0f / (float)N);
}